// Round 23
// baseline (44.799 us; speedup 1.0000x reference)
//
#include <hip/hip_runtime.h>

// LNCC loss: I,J [16,1,768,768] f32 -> out [16] f32
// R23 = R22 (scored 35.25us, 112 VGPR) with ONE change: masks applied at
// CONSUME, not at load. R17-R22's LD2 pre-masked (v_mul adjacent to each
// load) -> scheduler must wait for the load right at its issue point ->
// every prefetch collapsed to a full-latency stall (explains why depth-1->2,
// O-retention, and O-depth-2 were all ~null, and VALUBusy is stuck ~23%).
// LD2 is now pure raw loads (clamped addresses); CHUNKM/WACCM compute the
// row/col masks from indices and scale there — same multiply count, but the
// first load-dependent instruction is now ~2 chunks downstream.

constexpr int BATCH = 16;
constexpr int H = 768;
constexpr int W = 768;
constexpr float INV_WS = 1.0f / 81.0f;
constexpr float EPS = 3.0590232050182579e-07f;   // exp(-15)

constexpr int SEG = 12;                   // output rows per wave task
constexpr int NSEG = H / SEG;             // 64
constexpr int BANDW = 248;                // output cols per band (bands 0-2)
constexpr int NTHREADS = 256;             // 4 waves
constexpr int PPI = 200;                  // partials per image: 64*3 main + 8 band3

#define F4ADD(a, u)    { a.x += u.x; a.y += u.y; a.z += u.z; a.w += u.w; }
#define F4SUB(a, u)    { a.x -= u.x; a.y -= u.y; a.z -= u.z; a.w -= u.w; }
#define F4FMA(a, u, v) { a.x = fmaf(u.x, v.x, a.x); a.y = fmaf(u.y, v.y, a.y); \
                         a.z = fmaf(u.z, v.z, a.z); a.w = fmaf(u.w, v.w, a.w); }
#define F4FMS(a, u, v) { a.x = fmaf(u.x, -v.x, a.x); a.y = fmaf(u.y, -v.y, a.y); \
                         a.z = fmaf(u.z, -v.z, a.z); a.w = fmaf(u.w, -v.w, a.w); }

// h[e] = sum of cs cols [c0+e, c0+e+8]; output col = c0+4+e
#define HSUM_SHFL(c, h)                                                   \
    {                                                                     \
        const float s3 = c.w;                                             \
        const float s2 = c.w + c.z;                                       \
        const float s1 = s2 + c.y;                                        \
        const float s0 = s1 + c.x;          /* own total */               \
        const float p1 = c.x + c.y;                                       \
        const float p2 = p1 + c.z;                                        \
        const float pn = __shfl_down(s0, 1, 64);                          \
        const float q0 = __shfl_down(c.x, 2, 64);                         \
        const float q1 = __shfl_down(p1, 2, 64);                          \
        const float q2 = __shfl_down(p2, 2, 64);                          \
        const float q3 = __shfl_down(s0, 2, 64);                          \
        h[0] = s0 + pn + q0;                                              \
        h[1] = s1 + pn + q1;                                              \
        h[2] = s2 + pn + q2;                                              \
        h[3] = s3 + pn + q3;                                              \
    }

// RAW load of 2 rows (rbase, rbase+1), addresses clamped, NO masking here.
#define LD2(NI, NJ, rbase)                                                \
    {                                                                     \
        _Pragma("unroll")                                                 \
        for (int k = 0; k < 2; ++k) {                                     \
            const int rc = min(max((rbase) + k, 0), H - 1);               \
            NI[k] = *(const float4*)(Ib + (size_t)rc * W + ca);           \
            NJ[k] = *(const float4*)(Jb + (size_t)rc * W + ca);           \
        }                                                                 \
    }

// compute 2 output rows (rr, rr+1) from RAW in-batch (VI,VJ) holding rows
// rr+4..rr+5 and RAW out-batch (OI,OJ) holding rows rr-4..rr-3; masks
// computed and applied HERE (consume site).
#define CHUNKM(VI, VJ, OI, OJ, rr)                                        \
    _Pragma("unroll")                                                     \
    for (int k = 0; k < 2; ++k) {                                         \
        const float mi = ((rr) + 4 + k < H)  ? fm : 0.0f;                 \
        const float mo = ((rr) - 4 + k >= 0) ? fm : 0.0f;                 \
        float4 vi = VI[k], vj = VJ[k], oi = OI[k], oj = OJ[k];            \
        vi.x *= mi; vi.y *= mi; vi.z *= mi; vi.w *= mi;                   \
        vj.x *= mi; vj.y *= mi; vj.z *= mi; vj.w *= mi;                   \
        oi.x *= mo; oi.y *= mo; oi.z *= mo; oi.w *= mo;                   \
        oj.x *= mo; oj.y *= mo; oj.z *= mo; oj.w *= mo;                   \
        F4ADD(cs0, vi) F4ADD(cs1, vj)                                     \
        F4FMA(cs2, vi, vi) F4FMA(cs3, vj, vj) F4FMA(cs4, vi, vj)          \
        float hI[4], hJ[4], hII[4], hJJ[4], hIJ[4];                       \
        HSUM_SHFL(cs0, hI)                                                \
        HSUM_SHFL(cs1, hJ)                                                \
        HSUM_SHFL(cs2, hII)                                               \
        HSUM_SHFL(cs3, hJJ)                                               \
        HSUM_SHFL(cs4, hIJ)                                               \
        float rowsum = 0.0f;                                              \
        _Pragma("unroll")                                                 \
        for (int e = 0; e < 4; ++e) {                                     \
            const float u = -hI[e] * INV_WS;                              \
            const float cross = fmaf(u, hJ[e], hIJ[e]);                   \
            const float Ivar  = fmaf(u, hI[e], hII[e]);                   \
            const float Jvar  = fmaf(-hJ[e] * INV_WS, hJ[e], hJJ[e]);     \
            float prod = Ivar * Jvar;                                     \
            float num  = cross * cross;                                   \
            if (!(prod > EPS)) { prod = 1.0f; num = 1.0f; }               \
            float inv_;                                                   \
            asm("v_rcp_f32 %0, %1" : "=v"(inv_) : "v"(prod + EPS));       \
            rowsum = fmaf(num, inv_, rowsum);                             \
        }                                                                 \
        accum += live ? rowsum : 0.0f;                                    \
        F4SUB(cs0, oi) F4SUB(cs1, oj)                                     \
        F4FMS(cs2, oi, oi) F4FMS(cs3, oj, oj) F4FMS(cs4, oi, oj)          \
    }

__launch_bounds__(NTHREADS, 2)
__global__ void lncc_cm(const float* __restrict__ gI, const float* __restrict__ gJ,
                        float* __restrict__ part)
{
    const int lane = threadIdx.x & 63;
    const int band = threadIdx.x >> 6;                   // 0..3
    const int seg  = blockIdx.x;
    const int b    = blockIdx.y;

    int r0, c0;
    bool live;
    if (band < 3) {
        r0 = seg * SEG;
        c0 = band * BANDW - 4 + 4 * lane;                // own cs base col
        live = (lane <= 61);                             // bands 0-2 fully live
    } else {
        if (seg & 7) return;                             // wave-uniform exit
        const int rch = lane >> 3;                       // row-chunk 0..7
        const int cg  = lane & 7;                        // col-group 0..7
        r0 = (seg + rch) * SEG;                          // per-lane segment
        c0 = 740 + 4 * cg;                               // cs cols 740..771
        live = (cg <= 5);                                // outputs 744..767
    }
    const float fm = (c0 >= 0 && c0 + 3 < W) ? 1.0f : 0.0f;
    const int ca   = min(max(c0, 0), W - 4);             // 16B-aligned clamp

    const float* __restrict__ Ib = gI + (size_t)b * (H * W);
    const float* __restrict__ Jb = gJ + (size_t)b * (H * W);

    float4 cs0 = {0,0,0,0}, cs1 = {0,0,0,0}, cs2 = {0,0,0,0},
           cs3 = {0,0,0,0}, cs4 = {0,0,0,0};

    // ---- warm-up: 4 RAW 2-row chunks (rows r0-4 .. r0+3) ----
    float4 W0i[2], W0j[2], W1i[2], W1j[2], W2i[2], W2j[2], W3i[2], W3j[2];
    LD2(W0i, W0j, r0 - 4)
    LD2(W1i, W1j, r0 - 2)
    LD2(W2i, W2j, r0)
    LD2(W3i, W3j, r0 + 2)

    // ---- pipeline preload: in-chunks 0,1 (depth 2) + out-chunk 0 ----
    float4 I0i[2], I0j[2], I1i[2], I1j[2], I2i[2], I2j[2];
    float4 I3i[2], I3j[2], I4i[2], I4j[2], I5i[2], I5j[2];
    float4 OAi[2], OAj[2], OBi[2], OBj[2], OCi[2], OCj[2];
    LD2(I0i, I0j, r0 + 4)
    LD2(I1i, I1j, r0 + 6)
    LD2(OAi, OAj, r0 - 4)

    // warm-up accumulate: masks applied here (rows r0-4+... never >= H)
#define WACCM(WI, WJ, rbase)                                              \
    _Pragma("unroll")                                                     \
    for (int k = 0; k < 2; ++k) {                                         \
        const float mk = ((rbase) + k >= 0) ? fm : 0.0f;                  \
        float4 vi = WI[k], vj = WJ[k];                                    \
        vi.x *= mk; vi.y *= mk; vi.z *= mk; vi.w *= mk;                   \
        vj.x *= mk; vj.y *= mk; vj.z *= mk; vj.w *= mk;                   \
        F4ADD(cs0, vi) F4ADD(cs1, vj)                                     \
        F4FMA(cs2, vi, vi) F4FMA(cs3, vj, vj) F4FMA(cs4, vi, vj)          \
    }
    WACCM(W0i, W0j, r0 - 4)
    WACCM(W1i, W1j, r0 - 2)
    WACCM(W2i, W2j, r0)
    WACCM(W3i, W3j, r0 + 2)
#undef WACCM

    float accum = 0.0f;

    // ---- 6 pipelined chunks of 2 rows (SEG = 12) ----
    // in-loads 2 chunks ahead; out-loads ~2 ahead via 3-way O rotation.
    LD2(I2i, I2j, r0 + 8)   LD2(OBi, OBj, r0 - 2)
                            LD2(OCi, OCj, r0)       CHUNKM(I0i, I0j, OAi, OAj, r0)
    LD2(I3i, I3j, r0 + 10)  LD2(OAi, OAj, r0 + 2)   CHUNKM(I1i, I1j, OBi, OBj, r0 + 2)
    LD2(I4i, I4j, r0 + 12)  LD2(OBi, OBj, r0 + 4)   CHUNKM(I2i, I2j, OCi, OCj, r0 + 4)
    LD2(I5i, I5j, r0 + 14)  LD2(OCi, OCj, r0 + 6)   CHUNKM(I3i, I3j, OAi, OAj, r0 + 6)
                                                    CHUNKM(I4i, I4j, OBi, OBj, r0 + 8)
                                                    CHUNKM(I5i, I5j, OCi, OCj, r0 + 10)

    // ---- wave reduce -> one partial-store per wave (no LDS, no barrier) ----
    #pragma unroll
    for (int off = 32; off > 0; off >>= 1)
        accum += __shfl_xor(accum, off, 64);
    if (lane == 0) {
        if (band < 3)
            part[b * PPI + seg * 3 + band] = accum;      // slots 0..191
        else
            part[b * PPI + 192 + (seg >> 3)] = accum;    // slots 192..199
    }
}

// one wave per batch image: reduce 200 wave-partials, write final loss
__global__ void finalize2(const float* __restrict__ part, float* __restrict__ out) {
    const int b = threadIdx.y;              // 0..15 (one wave each)
    const int x = threadIdx.x;              // 0..63
    const int base = b * PPI;
    float v = part[base + x] + part[base + 64 + x] + part[base + 128 + x];
    if (x < 8) v += part[base + 192 + x];
    #pragma unroll
    for (int off = 32; off > 0; off >>= 1)
        v += __shfl_xor(v, off, 64);
    if (x == 0)
        out[b] = 1.0f - v * (1.0f / (float)(H * W));
}

extern "C" void kernel_launch(void* const* d_in, const int* in_sizes, int n_in,
                              void* d_out, int out_size, void* d_ws, size_t ws_size,
                              hipStream_t stream) {
    const float* I = (const float*)d_in[0];
    const float* J = (const float*)d_in[1];
    float* out  = (float*)d_out;
    float* part = (float*)d_ws;             // 16*200 floats, all written each launch

    dim3 grid(NSEG, BATCH);   // 64 x 16 = 1024 blocks; 3200 working waves
    lncc_cm<<<grid, NTHREADS, 0, stream>>>(I, J, part);

    finalize2<<<1, dim3(64, BATCH), 0, stream>>>(part, out);
}

// Round 24
// 36.885 us; speedup vs baseline: 1.2146x; 1.2146x over previous
//
#include <hip/hip_runtime.h>

// LNCC loss: I,J [16,1,768,768] f32 -> out [16] f32
// R24 = R21 (scored 35.94us, 112 VGPR, OA/OB out-ping-pong) + consume-site
// masking, registers funded by DROPPING R22's third O buffer.
// R23 tested consume-masks on top of O-depth-2: VGPR 112->128 + 4.8MB hot
// spill -> confounded regression. This is the clean test of the theory that
// pre-masking (v_mul adjacent to each load) pins the s_waitcnt at the load
// ISSUE site, collapsing all prefetch depth to zero (the only mechanism
// consistent with ~4x latency exposure surviving depth-2 on both streams).
// LD2 = raw clamped loads; CHUNKM/WACCM compute row-masks and scale at use.
// Validity gate: VGPR<=126 AND WRITE_SIZE<1KB, else experiment confounded.

constexpr int BATCH = 16;
constexpr int H = 768;
constexpr int W = 768;
constexpr float INV_WS = 1.0f / 81.0f;
constexpr float EPS = 3.0590232050182579e-07f;   // exp(-15)

constexpr int SEG = 12;                   // output rows per wave task
constexpr int NSEG = H / SEG;             // 64
constexpr int BANDW = 248;                // output cols per band (bands 0-2)
constexpr int NTHREADS = 256;             // 4 waves
constexpr int PPI = 200;                  // partials per image: 64*3 main + 8 band3

#define F4ADD(a, u)    { a.x += u.x; a.y += u.y; a.z += u.z; a.w += u.w; }
#define F4SUB(a, u)    { a.x -= u.x; a.y -= u.y; a.z -= u.z; a.w -= u.w; }
#define F4FMA(a, u, v) { a.x = fmaf(u.x, v.x, a.x); a.y = fmaf(u.y, v.y, a.y); \
                         a.z = fmaf(u.z, v.z, a.z); a.w = fmaf(u.w, v.w, a.w); }
#define F4FMS(a, u, v) { a.x = fmaf(u.x, -v.x, a.x); a.y = fmaf(u.y, -v.y, a.y); \
                         a.z = fmaf(u.z, -v.z, a.z); a.w = fmaf(u.w, -v.w, a.w); }

// h[e] = sum of cs cols [c0+e, c0+e+8]; output col = c0+4+e
#define HSUM_SHFL(c, h)                                                   \
    {                                                                     \
        const float s3 = c.w;                                             \
        const float s2 = c.w + c.z;                                       \
        const float s1 = s2 + c.y;                                        \
        const float s0 = s1 + c.x;          /* own total */               \
        const float p1 = c.x + c.y;                                       \
        const float p2 = p1 + c.z;                                        \
        const float pn = __shfl_down(s0, 1, 64);                          \
        const float q0 = __shfl_down(c.x, 2, 64);                         \
        const float q1 = __shfl_down(p1, 2, 64);                          \
        const float q2 = __shfl_down(p2, 2, 64);                          \
        const float q3 = __shfl_down(s0, 2, 64);                          \
        h[0] = s0 + pn + q0;                                              \
        h[1] = s1 + pn + q1;                                              \
        h[2] = s2 + pn + q2;                                              \
        h[3] = s3 + pn + q3;                                              \
    }

// RAW load of 2 rows (rbase, rbase+1): addresses clamped, NO masking here —
// no load-dependent VALU until the consuming chunk (~2 chunks downstream).
#define LD2(NI, NJ, rbase)                                                \
    {                                                                     \
        _Pragma("unroll")                                                 \
        for (int k = 0; k < 2; ++k) {                                     \
            const int rc = min(max((rbase) + k, 0), H - 1);               \
            NI[k] = *(const float4*)(Ib + (size_t)rc * W + ca);           \
            NJ[k] = *(const float4*)(Jb + (size_t)rc * W + ca);           \
        }                                                                 \
    }

// compute output rows rr, rr+1 from RAW in-batch (rows rr+4..5) and RAW
// out-batch (rows rr-4..-3); masks computed and applied HERE.
#define CHUNKM(VI, VJ, OI, OJ, rr)                                        \
    _Pragma("unroll")                                                     \
    for (int k = 0; k < 2; ++k) {                                         \
        const float mi = ((rr) + 4 + k < H)  ? fm : 0.0f;                 \
        const float mo = ((rr) - 4 + k >= 0) ? fm : 0.0f;                 \
        float4 vi = VI[k], vj = VJ[k], oi = OI[k], oj = OJ[k];            \
        vi.x *= mi; vi.y *= mi; vi.z *= mi; vi.w *= mi;                   \
        vj.x *= mi; vj.y *= mi; vj.z *= mi; vj.w *= mi;                   \
        oi.x *= mo; oi.y *= mo; oi.z *= mo; oi.w *= mo;                   \
        oj.x *= mo; oj.y *= mo; oj.z *= mo; oj.w *= mo;                   \
        F4ADD(cs0, vi) F4ADD(cs1, vj)                                     \
        F4FMA(cs2, vi, vi) F4FMA(cs3, vj, vj) F4FMA(cs4, vi, vj)          \
        float hI[4], hJ[4], hII[4], hJJ[4], hIJ[4];                       \
        HSUM_SHFL(cs0, hI)                                                \
        HSUM_SHFL(cs1, hJ)                                                \
        HSUM_SHFL(cs2, hII)                                               \
        HSUM_SHFL(cs3, hJJ)                                               \
        HSUM_SHFL(cs4, hIJ)                                               \
        float rowsum = 0.0f;                                              \
        _Pragma("unroll")                                                 \
        for (int e = 0; e < 4; ++e) {                                     \
            const float u = -hI[e] * INV_WS;                              \
            const float cross = fmaf(u, hJ[e], hIJ[e]);                   \
            const float Ivar  = fmaf(u, hI[e], hII[e]);                   \
            const float Jvar  = fmaf(-hJ[e] * INV_WS, hJ[e], hJJ[e]);     \
            float prod = Ivar * Jvar;                                     \
            float num  = cross * cross;                                   \
            if (!(prod > EPS)) { prod = 1.0f; num = 1.0f; }               \
            float inv_;                                                   \
            asm("v_rcp_f32 %0, %1" : "=v"(inv_) : "v"(prod + EPS));       \
            rowsum = fmaf(num, inv_, rowsum);                             \
        }                                                                 \
        accum += live ? rowsum : 0.0f;                                    \
        F4SUB(cs0, oi) F4SUB(cs1, oj)                                     \
        F4FMS(cs2, oi, oi) F4FMS(cs3, oj, oj) F4FMS(cs4, oi, oj)          \
    }

__launch_bounds__(NTHREADS, 2)
__global__ void lncc_cm2(const float* __restrict__ gI, const float* __restrict__ gJ,
                         float* __restrict__ part)
{
    const int lane = threadIdx.x & 63;
    const int band = threadIdx.x >> 6;                   // 0..3
    const int seg  = blockIdx.x;
    const int b    = blockIdx.y;

    int r0, c0;
    bool live;
    if (band < 3) {
        r0 = seg * SEG;
        c0 = band * BANDW - 4 + 4 * lane;                // own cs base col
        live = (lane <= 61);                             // bands 0-2 fully live
    } else {
        if (seg & 7) return;                             // wave-uniform exit
        const int rch = lane >> 3;                       // row-chunk 0..7
        const int cg  = lane & 7;                        // col-group 0..7
        r0 = (seg + rch) * SEG;                          // per-lane segment
        c0 = 740 + 4 * cg;                               // cs cols 740..771
        live = (cg <= 5);                                // outputs 744..767
    }
    const float fm = (c0 >= 0 && c0 + 3 < W) ? 1.0f : 0.0f;
    const int ca   = min(max(c0, 0), W - 4);             // 16B-aligned clamp

    const float* __restrict__ Ib = gI + (size_t)b * (H * W);
    const float* __restrict__ Jb = gJ + (size_t)b * (H * W);

    float4 cs0 = {0,0,0,0}, cs1 = {0,0,0,0}, cs2 = {0,0,0,0},
           cs3 = {0,0,0,0}, cs4 = {0,0,0,0};

    // ---- warm-up: 4 RAW 2-row chunks (rows r0-4 .. r0+3) ----
    float4 W0i[2], W0j[2], W1i[2], W1j[2], W2i[2], W2j[2], W3i[2], W3j[2];
    LD2(W0i, W0j, r0 - 4)
    LD2(W1i, W1j, r0 - 2)
    LD2(W2i, W2j, r0)
    LD2(W3i, W3j, r0 + 2)

    // ---- pipeline preload: in-chunks 0,1 (depth 2) + out-chunk 0 ----
    float4 I0i[2], I0j[2], I1i[2], I1j[2], I2i[2], I2j[2];
    float4 I3i[2], I3j[2], I4i[2], I4j[2], I5i[2], I5j[2];
    float4 OAi[2], OAj[2], OBi[2], OBj[2];
    LD2(I0i, I0j, r0 + 4)
    LD2(I1i, I1j, r0 + 6)
    LD2(OAi, OAj, r0 - 4)

    // warm-up accumulate: masks applied here (warmup rows never >= H)
#define WACCM(WI, WJ, rbase)                                              \
    _Pragma("unroll")                                                     \
    for (int k = 0; k < 2; ++k) {                                         \
        const float mk = ((rbase) + k >= 0) ? fm : 0.0f;                  \
        float4 vi = WI[k], vj = WJ[k];                                    \
        vi.x *= mk; vi.y *= mk; vi.z *= mk; vi.w *= mk;                   \
        vj.x *= mk; vj.y *= mk; vj.z *= mk; vj.w *= mk;                   \
        F4ADD(cs0, vi) F4ADD(cs1, vj)                                     \
        F4FMA(cs2, vi, vi) F4FMA(cs3, vj, vj) F4FMA(cs4, vi, vj)          \
    }
    WACCM(W0i, W0j, r0 - 4)
    WACCM(W1i, W1j, r0 - 2)
    WACCM(W2i, W2j, r0)
    WACCM(W3i, W3j, r0 + 2)
#undef WACCM

    float accum = 0.0f;

    // ---- 6 pipelined chunks of 2 rows (SEG = 12) ----
    // in-loads 2 chunks ahead (I0..I5); out-loads 1 chunk ahead (OA/OB).
    LD2(I2i, I2j, r0 + 8)   LD2(OBi, OBj, r0 - 2)   CHUNKM(I0i, I0j, OAi, OAj, r0)
    LD2(I3i, I3j, r0 + 10)  LD2(OAi, OAj, r0)       CHUNKM(I1i, I1j, OBi, OBj, r0 + 2)
    LD2(I4i, I4j, r0 + 12)  LD2(OBi, OBj, r0 + 2)   CHUNKM(I2i, I2j, OAi, OAj, r0 + 4)
    LD2(I5i, I5j, r0 + 14)  LD2(OAi, OAj, r0 + 4)   CHUNKM(I3i, I3j, OBi, OBj, r0 + 6)
                            LD2(OBi, OBj, r0 + 6)   CHUNKM(I4i, I4j, OAi, OAj, r0 + 8)
                                                    CHUNKM(I5i, I5j, OBi, OBj, r0 + 10)

    // ---- wave reduce -> one partial-store per wave (no LDS, no barrier) ----
    #pragma unroll
    for (int off = 32; off > 0; off >>= 1)
        accum += __shfl_xor(accum, off, 64);
    if (lane == 0) {
        if (band < 3)
            part[b * PPI + seg * 3 + band] = accum;      // slots 0..191
        else
            part[b * PPI + 192 + (seg >> 3)] = accum;    // slots 192..199
    }
}

// one wave per batch image: reduce 200 wave-partials, write final loss
__global__ void finalize2(const float* __restrict__ part, float* __restrict__ out) {
    const int b = threadIdx.y;              // 0..15 (one wave each)
    const int x = threadIdx.x;              // 0..63
    const int base = b * PPI;
    float v = part[base + x] + part[base + 64 + x] + part[base + 128 + x];
    if (x < 8) v += part[base + 192 + x];
    #pragma unroll
    for (int off = 32; off > 0; off >>= 1)
        v += __shfl_xor(v, off, 64);
    if (x == 0)
        out[b] = 1.0f - v * (1.0f / (float)(H * W));
}

extern "C" void kernel_launch(void* const* d_in, const int* in_sizes, int n_in,
                              void* d_out, int out_size, void* d_ws, size_t ws_size,
                              hipStream_t stream) {
    const float* I = (const float*)d_in[0];
    const float* J = (const float*)d_in[1];
    float* out  = (float*)d_out;
    float* part = (float*)d_ws;             // 16*200 floats, all written each launch

    dim3 grid(NSEG, BATCH);   // 64 x 16 = 1024 blocks; 3200 working waves
    lncc_cm2<<<grid, NTHREADS, 0, stream>>>(I, J, part);

    finalize2<<<1, dim3(64, BATCH), 0, stream>>>(part, out);
}

// Round 25
// 36.494 us; speedup vs baseline: 1.2276x; 1.0107x over previous
//
#include <hip/hip_runtime.h>

// LNCC loss: I,J [16,1,768,768] f32 -> out [16] f32
// R25 = R22 (best: scored 35.25us, 112 VGPR, band-3 packing, I-depth-2 +
// O-depth-2 3-way-rotation register pipeline, pre-masked loads) + T1
// XCD-chunked block swizzle. Dispatch round-robins consecutive block ids
// across the 8 XCDs, so each XCD's resident blocks touch all 16 images ->
// the 8-rows-later out-row re-read (128KB/CU reuse window) misses L2.
// Remap (bijective, 1024%8==0): phys id -> xcd=phys&7, task=xcd*128+(phys>>3)
// so each XCD covers exactly 2 images contiguously (9.4MB footprint vs 4MB
// L2 + halo sharing between adjacent segs on the same XCD).
// R23/R24 falsified consume-site masking; R19 falsified sched_barrier;
// pre-masked LD2 retained.

constexpr int BATCH = 16;
constexpr int H = 768;
constexpr int W = 768;
constexpr float INV_WS = 1.0f / 81.0f;
constexpr float EPS = 3.0590232050182579e-07f;   // exp(-15)

constexpr int SEG = 12;                   // output rows per wave task
constexpr int NSEG = H / SEG;             // 64
constexpr int BANDW = 248;                // output cols per band (bands 0-2)
constexpr int NTHREADS = 256;             // 4 waves
constexpr int PPI = 200;                  // partials per image: 64*3 main + 8 band3

#define F4ADD(a, u)    { a.x += u.x; a.y += u.y; a.z += u.z; a.w += u.w; }
#define F4SUB(a, u)    { a.x -= u.x; a.y -= u.y; a.z -= u.z; a.w -= u.w; }
#define F4FMA(a, u, v) { a.x = fmaf(u.x, v.x, a.x); a.y = fmaf(u.y, v.y, a.y); \
                         a.z = fmaf(u.z, v.z, a.z); a.w = fmaf(u.w, v.w, a.w); }
#define F4FMS(a, u, v) { a.x = fmaf(u.x, -v.x, a.x); a.y = fmaf(u.y, -v.y, a.y); \
                         a.z = fmaf(u.z, -v.z, a.z); a.w = fmaf(u.w, -v.w, a.w); }

// h[e] = sum of cs cols [c0+e, c0+e+8]; output col = c0+4+e
#define HSUM_SHFL(c, h)                                                   \
    {                                                                     \
        const float s3 = c.w;                                             \
        const float s2 = c.w + c.z;                                       \
        const float s1 = s2 + c.y;                                        \
        const float s0 = s1 + c.x;          /* own total */               \
        const float p1 = c.x + c.y;                                       \
        const float p2 = p1 + c.z;                                        \
        const float pn = __shfl_down(s0, 1, 64);                          \
        const float q0 = __shfl_down(c.x, 2, 64);                         \
        const float q1 = __shfl_down(p1, 2, 64);                          \
        const float q2 = __shfl_down(p2, 2, 64);                          \
        const float q3 = __shfl_down(s0, 2, 64);                          \
        h[0] = s0 + pn + q0;                                              \
        h[1] = s1 + pn + q1;                                              \
        h[2] = s2 + pn + q2;                                              \
        h[3] = s3 + pn + q3;                                              \
    }

// load 2 rows (rbase, rbase+1) PRE-MASKED (addr clamped, scaled by row-mask*fm)
#define LD2(NI, NJ, rbase)                                                \
    {                                                                     \
        _Pragma("unroll")                                                 \
        for (int k = 0; k < 2; ++k) {                                     \
            const int rr = (rbase) + k;                                   \
            const int rc = min(max(rr, 0), H - 1);                        \
            const float mk = (rr >= 0 && rr < H) ? fm : 0.0f;             \
            float4 ti = *(const float4*)(Ib + (size_t)rc * W + ca);       \
            float4 tj = *(const float4*)(Jb + (size_t)rc * W + ca);       \
            ti.x *= mk; ti.y *= mk; ti.z *= mk; ti.w *= mk;               \
            tj.x *= mk; tj.y *= mk; tj.z *= mk; tj.w *= mk;               \
            NI[k] = ti; NJ[k] = tj;                                       \
        }                                                                 \
    }

// compute 2 output rows from pre-masked in-batch (VI,VJ) and out-batch (OI,OJ)
#define CHUNK(VI, VJ, OI, OJ)                                             \
    _Pragma("unroll")                                                     \
    for (int k = 0; k < 2; ++k) {                                         \
        F4ADD(cs0, VI[k]) F4ADD(cs1, VJ[k])                               \
        F4FMA(cs2, VI[k], VI[k]) F4FMA(cs3, VJ[k], VJ[k])                 \
        F4FMA(cs4, VI[k], VJ[k])                                          \
        float hI[4], hJ[4], hII[4], hJJ[4], hIJ[4];                       \
        HSUM_SHFL(cs0, hI)                                                \
        HSUM_SHFL(cs1, hJ)                                                \
        HSUM_SHFL(cs2, hII)                                               \
        HSUM_SHFL(cs3, hJJ)                                               \
        HSUM_SHFL(cs4, hIJ)                                               \
        float rowsum = 0.0f;                                              \
        _Pragma("unroll")                                                 \
        for (int e = 0; e < 4; ++e) {                                     \
            const float u = -hI[e] * INV_WS;                              \
            const float cross = fmaf(u, hJ[e], hIJ[e]);                   \
            const float Ivar  = fmaf(u, hI[e], hII[e]);                   \
            const float Jvar  = fmaf(-hJ[e] * INV_WS, hJ[e], hJJ[e]);     \
            float prod = Ivar * Jvar;                                     \
            float num  = cross * cross;                                   \
            if (!(prod > EPS)) { prod = 1.0f; num = 1.0f; }               \
            float inv_;                                                   \
            asm("v_rcp_f32 %0, %1" : "=v"(inv_) : "v"(prod + EPS));       \
            rowsum = fmaf(num, inv_, rowsum);                             \
        }                                                                 \
        accum += live ? rowsum : 0.0f;                                    \
        F4SUB(cs0, OI[k]) F4SUB(cs1, OJ[k])                               \
        F4FMS(cs2, OI[k], OI[k]) F4FMS(cs3, OJ[k], OJ[k])                 \
        F4FMS(cs4, OI[k], OJ[k])                                          \
    }

__launch_bounds__(NTHREADS, 2)
__global__ void lncc_xcd(const float* __restrict__ gI, const float* __restrict__ gJ,
                         float* __restrict__ part)
{
    const int lane = threadIdx.x & 63;
    const int band = threadIdx.x >> 6;                   // 0..3

    // T1 XCD-chunked swizzle: dispatch id -> contiguous per-XCD task chunk.
    // 1024 blocks, 8 XCDs: xcd = phys&7 (round-robin dispatch), each XCD
    // gets tasks [xcd*128, (xcd+1)*128) = 2 whole images, segs in order.
    const int phys = blockIdx.y * gridDim.x + blockIdx.x;   // 0..1023
    const int task = (phys & 7) * 128 + (phys >> 3);        // bijective
    const int seg  = task & 63;
    const int b    = task >> 6;

    int r0, c0;
    bool live;
    if (band < 3) {
        r0 = seg * SEG;
        c0 = band * BANDW - 4 + 4 * lane;                // own cs base col
        live = (lane <= 61);                             // bands 0-2 fully live
    } else {
        if (seg & 7) return;                             // wave-uniform exit
        const int rch = lane >> 3;                       // row-chunk 0..7
        const int cg  = lane & 7;                        // col-group 0..7
        r0 = (seg + rch) * SEG;                          // per-lane segment
        c0 = 740 + 4 * cg;                               // cs cols 740..771
        live = (cg <= 5);                                // outputs 744..767
    }
    const float fm = (c0 >= 0 && c0 + 3 < W) ? 1.0f : 0.0f;
    const int ca   = min(max(c0, 0), W - 4);             // 16B-aligned clamp

    const float* __restrict__ Ib = gI + (size_t)b * (H * W);
    const float* __restrict__ Jb = gJ + (size_t)b * (H * W);

    float4 cs0 = {0,0,0,0}, cs1 = {0,0,0,0}, cs2 = {0,0,0,0},
           cs3 = {0,0,0,0}, cs4 = {0,0,0,0};

    // ---- warm-up: 4 pre-masked 2-row chunks (rows r0-4 .. r0+3) ----
    float4 W0i[2], W0j[2], W1i[2], W1j[2], W2i[2], W2j[2], W3i[2], W3j[2];
    LD2(W0i, W0j, r0 - 4)
    LD2(W1i, W1j, r0 - 2)
    LD2(W2i, W2j, r0)
    LD2(W3i, W3j, r0 + 2)

    // ---- pipeline preload: in-chunks 0,1 (depth 2) + out-chunk 0 ----
    float4 I0i[2], I0j[2], I1i[2], I1j[2], I2i[2], I2j[2];
    float4 I3i[2], I3j[2], I4i[2], I4j[2], I5i[2], I5j[2];
    float4 OAi[2], OAj[2], OBi[2], OBj[2], OCi[2], OCj[2];
    LD2(I0i, I0j, r0 + 4)
    LD2(I1i, I1j, r0 + 6)
    LD2(OAi, OAj, r0 - 4)

    // warm-up accumulate (~700 cy) covers the preload latency
#define WACC(WI, WJ)                                                      \
    _Pragma("unroll")                                                     \
    for (int k = 0; k < 2; ++k) {                                         \
        F4ADD(cs0, WI[k]) F4ADD(cs1, WJ[k])                               \
        F4FMA(cs2, WI[k], WI[k]) F4FMA(cs3, WJ[k], WJ[k])                 \
        F4FMA(cs4, WI[k], WJ[k])                                          \
    }
    WACC(W0i, W0j) WACC(W1i, W1j) WACC(W2i, W2j) WACC(W3i, W3j)
#undef WACC

    float accum = 0.0f;

    // ---- 6 pipelined chunks of 2 rows (SEG = 12) ----
    // in-loads 2 chunks ahead (I0..I5); out-loads ~2 ahead via 3-way O rotation.
    LD2(I2i, I2j, r0 + 8)   LD2(OBi, OBj, r0 - 2)
                            LD2(OCi, OCj, r0)       CHUNK(I0i, I0j, OAi, OAj)
    LD2(I3i, I3j, r0 + 10)  LD2(OAi, OAj, r0 + 2)   CHUNK(I1i, I1j, OBi, OBj)
    LD2(I4i, I4j, r0 + 12)  LD2(OBi, OBj, r0 + 4)   CHUNK(I2i, I2j, OCi, OCj)
    LD2(I5i, I5j, r0 + 14)  LD2(OCi, OCj, r0 + 6)   CHUNK(I3i, I3j, OAi, OAj)
                                                    CHUNK(I4i, I4j, OBi, OBj)
                                                    CHUNK(I5i, I5j, OCi, OCj)

    // ---- wave reduce -> one partial-store per wave (no LDS, no barrier) ----
    #pragma unroll
    for (int off = 32; off > 0; off >>= 1)
        accum += __shfl_xor(accum, off, 64);
    if (lane == 0) {
        if (band < 3)
            part[b * PPI + seg * 3 + band] = accum;      // slots 0..191
        else
            part[b * PPI + 192 + (seg >> 3)] = accum;    // slots 192..199
    }
}

// one wave per batch image: reduce 200 wave-partials, write final loss
__global__ void finalize2(const float* __restrict__ part, float* __restrict__ out) {
    const int b = threadIdx.y;              // 0..15 (one wave each)
    const int x = threadIdx.x;              // 0..63
    const int base = b * PPI;
    float v = part[base + x] + part[base + 64 + x] + part[base + 128 + x];
    if (x < 8) v += part[base + 192 + x];
    #pragma unroll
    for (int off = 32; off > 0; off >>= 1)
        v += __shfl_xor(v, off, 64);
    if (x == 0)
        out[b] = 1.0f - v * (1.0f / (float)(H * W));
}

extern "C" void kernel_launch(void* const* d_in, const int* in_sizes, int n_in,
                              void* d_out, int out_size, void* d_ws, size_t ws_size,
                              hipStream_t stream) {
    const float* I = (const float*)d_in[0];
    const float* J = (const float*)d_in[1];
    float* out  = (float*)d_out;
    float* part = (float*)d_ws;             // 16*200 floats, all written each launch

    dim3 grid(NSEG, BATCH);   // 64 x 16 = 1024 blocks; 3200 working waves
    lncc_xcd<<<grid, NTHREADS, 0, stream>>>(I, J, part);

    finalize2<<<1, dim3(64, BATCH), 0, stream>>>(part, out);
}

// Round 26
// 35.305 us; speedup vs baseline: 1.2689x; 1.0337x over previous
//
#include <hip/hip_runtime.h>

// LNCC loss: I,J [16,1,768,768] f32 -> out [16] f32
// R26 = R22 EXACTLY (best measured: scored 35.25us, kernel 39.6us, 112 VGPR,
// zero spill). Revert of R25's XCD swizzle (FETCH -31% but time +3%: proved
// the residual stall is not memory service time; swizzle also cost +12 VGPR).
// Structure: band-3 packed waves (3200 working waves), 2-row-chunk register
// pipeline with I-depth-2 + O-depth-2 (3-way O rotation), pre-masked loads,
// shuffle-tree horizontal 9-sums, per-wave partial stores + finalize2.
// Falsified levers (do not retry): sched_barrier(0) [R19: spill],
// consume-site masks [R24: null], O-register-retention [R18: forces depth-1],
// XCD swizzle [R25], extra TLP [R7/R11], LDS staging/colsum-share [R9/R10].

constexpr int BATCH = 16;
constexpr int H = 768;
constexpr int W = 768;
constexpr float INV_WS = 1.0f / 81.0f;
constexpr float EPS = 3.0590232050182579e-07f;   // exp(-15)

constexpr int SEG = 12;                   // output rows per wave task
constexpr int NSEG = H / SEG;             // 64
constexpr int BANDW = 248;                // output cols per band (bands 0-2)
constexpr int NTHREADS = 256;             // 4 waves
constexpr int PPI = 200;                  // partials per image: 64*3 main + 8 band3

#define F4ADD(a, u)    { a.x += u.x; a.y += u.y; a.z += u.z; a.w += u.w; }
#define F4SUB(a, u)    { a.x -= u.x; a.y -= u.y; a.z -= u.z; a.w -= u.w; }
#define F4FMA(a, u, v) { a.x = fmaf(u.x, v.x, a.x); a.y = fmaf(u.y, v.y, a.y); \
                         a.z = fmaf(u.z, v.z, a.z); a.w = fmaf(u.w, v.w, a.w); }
#define F4FMS(a, u, v) { a.x = fmaf(u.x, -v.x, a.x); a.y = fmaf(u.y, -v.y, a.y); \
                         a.z = fmaf(u.z, -v.z, a.z); a.w = fmaf(u.w, -v.w, a.w); }

// h[e] = sum of cs cols [c0+e, c0+e+8]; output col = c0+4+e
#define HSUM_SHFL(c, h)                                                   \
    {                                                                     \
        const float s3 = c.w;                                             \
        const float s2 = c.w + c.z;                                       \
        const float s1 = s2 + c.y;                                        \
        const float s0 = s1 + c.x;          /* own total */               \
        const float p1 = c.x + c.y;                                       \
        const float p2 = p1 + c.z;                                        \
        const float pn = __shfl_down(s0, 1, 64);                          \
        const float q0 = __shfl_down(c.x, 2, 64);                         \
        const float q1 = __shfl_down(p1, 2, 64);                          \
        const float q2 = __shfl_down(p2, 2, 64);                          \
        const float q3 = __shfl_down(s0, 2, 64);                          \
        h[0] = s0 + pn + q0;                                              \
        h[1] = s1 + pn + q1;                                              \
        h[2] = s2 + pn + q2;                                              \
        h[3] = s3 + pn + q3;                                              \
    }

// load 2 rows (rbase, rbase+1) PRE-MASKED (addr clamped, scaled by row-mask*fm)
#define LD2(NI, NJ, rbase)                                                \
    {                                                                     \
        _Pragma("unroll")                                                 \
        for (int k = 0; k < 2; ++k) {                                     \
            const int rr = (rbase) + k;                                   \
            const int rc = min(max(rr, 0), H - 1);                        \
            const float mk = (rr >= 0 && rr < H) ? fm : 0.0f;             \
            float4 ti = *(const float4*)(Ib + (size_t)rc * W + ca);       \
            float4 tj = *(const float4*)(Jb + (size_t)rc * W + ca);       \
            ti.x *= mk; ti.y *= mk; ti.z *= mk; ti.w *= mk;               \
            tj.x *= mk; tj.y *= mk; tj.z *= mk; tj.w *= mk;               \
            NI[k] = ti; NJ[k] = tj;                                       \
        }                                                                 \
    }

// compute 2 output rows from pre-masked in-batch (VI,VJ) and out-batch (OI,OJ)
#define CHUNK(VI, VJ, OI, OJ)                                             \
    _Pragma("unroll")                                                     \
    for (int k = 0; k < 2; ++k) {                                         \
        F4ADD(cs0, VI[k]) F4ADD(cs1, VJ[k])                               \
        F4FMA(cs2, VI[k], VI[k]) F4FMA(cs3, VJ[k], VJ[k])                 \
        F4FMA(cs4, VI[k], VJ[k])                                          \
        float hI[4], hJ[4], hII[4], hJJ[4], hIJ[4];                       \
        HSUM_SHFL(cs0, hI)                                                \
        HSUM_SHFL(cs1, hJ)                                                \
        HSUM_SHFL(cs2, hII)                                               \
        HSUM_SHFL(cs3, hJJ)                                               \
        HSUM_SHFL(cs4, hIJ)                                               \
        float rowsum = 0.0f;                                              \
        _Pragma("unroll")                                                 \
        for (int e = 0; e < 4; ++e) {                                     \
            const float u = -hI[e] * INV_WS;                              \
            const float cross = fmaf(u, hJ[e], hIJ[e]);                   \
            const float Ivar  = fmaf(u, hI[e], hII[e]);                   \
            const float Jvar  = fmaf(-hJ[e] * INV_WS, hJ[e], hJJ[e]);     \
            float prod = Ivar * Jvar;                                     \
            float num  = cross * cross;                                   \
            if (!(prod > EPS)) { prod = 1.0f; num = 1.0f; }               \
            float inv_;                                                   \
            asm("v_rcp_f32 %0, %1" : "=v"(inv_) : "v"(prod + EPS));       \
            rowsum = fmaf(num, inv_, rowsum);                             \
        }                                                                 \
        accum += live ? rowsum : 0.0f;                                    \
        F4SUB(cs0, OI[k]) F4SUB(cs1, OJ[k])                               \
        F4FMS(cs2, OI[k], OI[k]) F4FMS(cs3, OJ[k], OJ[k])                 \
        F4FMS(cs4, OI[k], OJ[k])                                          \
    }

__launch_bounds__(NTHREADS, 2)
__global__ void lncc_o2(const float* __restrict__ gI, const float* __restrict__ gJ,
                        float* __restrict__ part)
{
    const int lane = threadIdx.x & 63;
    const int band = threadIdx.x >> 6;                   // 0..3
    const int seg  = blockIdx.x;
    const int b    = blockIdx.y;

    int r0, c0;
    bool live;
    if (band < 3) {
        r0 = seg * SEG;
        c0 = band * BANDW - 4 + 4 * lane;                // own cs base col
        live = (lane <= 61);                             // bands 0-2 fully live
    } else {
        if (seg & 7) return;                             // wave-uniform exit
        const int rch = lane >> 3;                       // row-chunk 0..7
        const int cg  = lane & 7;                        // col-group 0..7
        r0 = (seg + rch) * SEG;                          // per-lane segment
        c0 = 740 + 4 * cg;                               // cs cols 740..771
        live = (cg <= 5);                                // outputs 744..767
    }
    const float fm = (c0 >= 0 && c0 + 3 < W) ? 1.0f : 0.0f;
    const int ca   = min(max(c0, 0), W - 4);             // 16B-aligned clamp

    const float* __restrict__ Ib = gI + (size_t)b * (H * W);
    const float* __restrict__ Jb = gJ + (size_t)b * (H * W);

    float4 cs0 = {0,0,0,0}, cs1 = {0,0,0,0}, cs2 = {0,0,0,0},
           cs3 = {0,0,0,0}, cs4 = {0,0,0,0};

    // ---- warm-up: 4 pre-masked 2-row chunks (rows r0-4 .. r0+3) ----
    float4 W0i[2], W0j[2], W1i[2], W1j[2], W2i[2], W2j[2], W3i[2], W3j[2];
    LD2(W0i, W0j, r0 - 4)
    LD2(W1i, W1j, r0 - 2)
    LD2(W2i, W2j, r0)
    LD2(W3i, W3j, r0 + 2)

    // ---- pipeline preload: in-chunks 0,1 (depth 2) + out-chunk 0 ----
    float4 I0i[2], I0j[2], I1i[2], I1j[2], I2i[2], I2j[2];
    float4 I3i[2], I3j[2], I4i[2], I4j[2], I5i[2], I5j[2];
    float4 OAi[2], OAj[2], OBi[2], OBj[2], OCi[2], OCj[2];
    LD2(I0i, I0j, r0 + 4)
    LD2(I1i, I1j, r0 + 6)
    LD2(OAi, OAj, r0 - 4)

    // warm-up accumulate (~700 cy) covers the preload latency
#define WACC(WI, WJ)                                                      \
    _Pragma("unroll")                                                     \
    for (int k = 0; k < 2; ++k) {                                         \
        F4ADD(cs0, WI[k]) F4ADD(cs1, WJ[k])                               \
        F4FMA(cs2, WI[k], WI[k]) F4FMA(cs3, WJ[k], WJ[k])                 \
        F4FMA(cs4, WI[k], WJ[k])                                          \
    }
    WACC(W0i, W0j) WACC(W1i, W1j) WACC(W2i, W2j) WACC(W3i, W3j)
#undef WACC

    float accum = 0.0f;

    // ---- 6 pipelined chunks of 2 rows (SEG = 12) ----
    // in-loads 2 chunks ahead (I0..I5); out-loads ~2 ahead via 3-way O rotation.
    LD2(I2i, I2j, r0 + 8)   LD2(OBi, OBj, r0 - 2)
                            LD2(OCi, OCj, r0)       CHUNK(I0i, I0j, OAi, OAj)
    LD2(I3i, I3j, r0 + 10)  LD2(OAi, OAj, r0 + 2)   CHUNK(I1i, I1j, OBi, OBj)
    LD2(I4i, I4j, r0 + 12)  LD2(OBi, OBj, r0 + 4)   CHUNK(I2i, I2j, OCi, OCj)
    LD2(I5i, I5j, r0 + 14)  LD2(OCi, OCj, r0 + 6)   CHUNK(I3i, I3j, OAi, OAj)
                                                    CHUNK(I4i, I4j, OBi, OBj)
                                                    CHUNK(I5i, I5j, OCi, OCj)

    // ---- wave reduce -> one partial-store per wave (no LDS, no barrier) ----
    #pragma unroll
    for (int off = 32; off > 0; off >>= 1)
        accum += __shfl_xor(accum, off, 64);
    if (lane == 0) {
        if (band < 3)
            part[b * PPI + seg * 3 + band] = accum;      // slots 0..191
        else
            part[b * PPI + 192 + (seg >> 3)] = accum;    // slots 192..199
    }
}

// one wave per batch image: reduce 200 wave-partials, write final loss
__global__ void finalize2(const float* __restrict__ part, float* __restrict__ out) {
    const int b = threadIdx.y;              // 0..15 (one wave each)
    const int x = threadIdx.x;              // 0..63
    const int base = b * PPI;
    float v = part[base + x] + part[base + 64 + x] + part[base + 128 + x];
    if (x < 8) v += part[base + 192 + x];
    #pragma unroll
    for (int off = 32; off > 0; off >>= 1)
        v += __shfl_xor(v, off, 64);
    if (x == 0)
        out[b] = 1.0f - v * (1.0f / (float)(H * W));
}

extern "C" void kernel_launch(void* const* d_in, const int* in_sizes, int n_in,
                              void* d_out, int out_size, void* d_ws, size_t ws_size,
                              hipStream_t stream) {
    const float* I = (const float*)d_in[0];
    const float* J = (const float*)d_in[1];
    float* out  = (float*)d_out;
    float* part = (float*)d_ws;             // 16*200 floats, all written each launch

    dim3 grid(NSEG, BATCH);   // 64 x 16 = 1024 blocks; 3200 working waves
    lncc_o2<<<grid, NTHREADS, 0, stream>>>(I, J, part);

    finalize2<<<1, dim3(64, BATCH), 0, stream>>>(part, out);
}